// Round 7
// baseline (1334.300 us; speedup 1.0000x reference)
//
#include <hip/hip_runtime.h>
#include <hip/hip_bf16.h>
#include <math.h>

#define VAR_N 4
#define LEVELS 17
#define NCELLS 56
#define PRED_N 12
#define TSTEPS 4096
#define TROWS (TSTEPS + PRED_N)
#define DT 0.1f
#define RPB 8
#define LOG2E 1.44269504088896340736f

static __device__ __forceinline__ float rl(float x, int lane) {
    return __int_as_float(__builtin_amdgcn_readlane(__float_as_int(x), lane));
}
static __device__ __forceinline__ float rcpf(float x) {
    return __builtin_amdgcn_rcpf(x);
}

// ---------------------------------------------------------------------------
// Kernel 1: preproc encoder (68->68 x5) FUSED with gprep.
// pre never hits HBM: the block's 8 output rows stay in LDS and are folded
// straight into g[v][j][t] = LOG2E*(b[v][j] + sum_l u*wx).
// ---------------------------------------------------------------------------
__global__ void pre_g_kernel(const float* __restrict__ x,
                             const float* __restrict__ w1, const float* __restrict__ b1,
                             const float* __restrict__ w2, const float* __restrict__ b2,
                             const float* __restrict__ w3, const float* __restrict__ b3,
                             const float* __restrict__ w4, const float* __restrict__ b4,
                             const float* __restrict__ w5, const float* __restrict__ b5,
                             const float* __restrict__ wx, const float* __restrict__ bvec,
                             float* __restrict__ g) {
    __shared__ float lds[2 * RPB * 68];
    float* bufA = lds;
    float* bufB = lds + RPB * 68;
    const int r0 = blockIdx.x * RPB;          // 4096 % 8 == 0, no row guard needed
    const int tid = threadIdx.x;

    for (int idx = tid; idx < RPB * 68; idx += 256)
        bufA[idx] = x[(size_t)r0 * 68 + idx];
    __syncthreads();

    const float* Ws[5] = {w1, w2, w3, w4, w5};
    const float* Bs[5] = {b1, b2, b3, b4, b5};
    for (int L = 0; L < 5; ++L) {
        const float* __restrict__ W = Ws[L];
        const bool act = (L < 4);
        if (tid < 68) {
            const int j = tid;
            float acc[RPB];
            float bj = Bs[L][j];
#pragma unroll
            for (int r = 0; r < RPB; ++r) acc[r] = bj;
            for (int k = 0; k + 4 <= 68; k += 4) {
                float w0v = W[(k + 0) * 68 + j];
                float w1v = W[(k + 1) * 68 + j];
                float w2v = W[(k + 2) * 68 + j];
                float w3v = W[(k + 3) * 68 + j];
#pragma unroll
                for (int r = 0; r < RPB; ++r) {
                    const float4 hx = *(const float4*)(bufA + r * 68 + k);
                    acc[r] = fmaf(hx.x, w0v, fmaf(hx.y, w1v,
                              fmaf(hx.z, w2v, fmaf(hx.w, w3v, acc[r]))));
                }
            }
#pragma unroll
            for (int r = 0; r < RPB; ++r)
                bufB[r * 68 + j] = act ? fmaxf(acc[r], 0.f) : acc[r];
        }
        __syncthreads();
        float* t = bufA; bufA = bufB; bufB = t;
    }

    // epilogue: fold into g (transposed [v][j][t], LOG2E-scaled)
    for (int idx = tid; idx < RPB * 4 * NCELLS; idx += 256) {
        int r = idx / 224;
        int rem = idx - r * 224;
        int q = rem / NCELLS;
        int j = rem - q * NCELLS;
        int gr = r0 + r;
        int v = gr >> 10;
        int trow = ((gr & 1023) << 2) + q;
        const float* arow = bufA + r * 68 + q * LEVELS;
        float acc = bvec[v * NCELLS + j];
#pragma unroll
        for (int l = 0; l < LEVELS; ++l)
            acc = fmaf(arow[l], wx[(v * LEVELS + l) * NCELLS + j], acc);
        g[((size_t)(v * NCELLS + j)) * TSTEPS + trow] = acc * LOG2E;
    }
}

// ---------------------------------------------------------------------------
// Kernel 2: sequential LTC scan, 1 wave/var, 1 wave/EU, with the output
// projection FUSED in: during cell(t), hv = broadcast(h_t) is already in
// registers, so vs[t-1] = h_t@wout+bout costs 28 independent pk-fmas that
// fill the DS-stall slots. H is never materialized.
// ---------------------------------------------------------------------------
__global__ void __launch_bounds__(64, 1) scan_kernel(
    const float* __restrict__ g, const float* __restrict__ wh,
    const float* __restrict__ a, const float* __restrict__ tau,
    const float* __restrict__ wx, const float* __restrict__ wout,
    const float* __restrict__ bout, const float* __restrict__ b,
    float* __restrict__ vs_t) {
    typedef float v2 __attribute__((ext_vector_type(2)));
    const int v = blockIdx.x;
    const int lane = threadIdx.x;
    const bool active = lane < NCELLS;
    const int j = active ? lane : (NCELLS - 1);
    __shared__ __align__(16) float hbuf[64];

    // lane j: column j of wh (LOG2E-scaled), 28 packed pairs over k
    v2 whp[28];
#pragma unroll
    for (int q = 0; q < 28; ++q) {
        float w0 = active ? wh[((size_t)v * NCELLS + 2 * q + 0) * NCELLS + lane] * LOG2E : 0.f;
        float w1 = active ? wh[((size_t)v * NCELLS + 2 * q + 1) * NCELLS + lane] * LOG2E : 0.f;
        v2 t; t.x = w0; t.y = w1;
        whp[q] = t;
    }
    // lane l (<17): wout[:, l] as 28 packed pairs (for inline projection)
    v2 wtcp[28];
#pragma unroll
    for (int q = 0; q < 28; ++q) {
        float w0 = (lane < LEVELS) ? wout[((size_t)v * NCELLS + 2 * q + 0) * LEVELS + lane] : 0.f;
        float w1 = (lane < LEVELS) ? wout[((size_t)v * NCELLS + 2 * q + 1) * LEVELS + lane] : 0.f;
        v2 t; t.x = w0; t.y = w1;
        wtcp[q] = t;
    }
    const float alpha = active ? DT * a[v * NCELLS + lane] : 0.f;
    const float cden = active ? 1.f + DT / (tau[v * NCELLS + lane] + 0.5f) : 1.f;
    const float boutl = (lane < LEVELS) ? bout[v * LEVELS + lane] : 0.f;

    const float4* __restrict__ gv4 = (const float4*)(g + ((size_t)v * NCELLS + j) * TSTEPS);
    float* __restrict__ vsb = vs_t + (size_t)v * LEVELS + lane;   // stride 68 per t

    auto cell = [&](float h, float gcur, float& vsv) -> float {
        hbuf[lane] = h;   // ds_write; same-wave DS pipe ordering, no barrier
        const float4* h4 = (const float4*)hbuf;
        float4 hv[14];
#pragma unroll
        for (int q = 0; q < 14; ++q) hv[q] = h4[q];   // 14 ds_read_b128, broadcast
        v2 a0 = {0.f, 0.f}, a1 = {0.f, 0.f}, a2 = {0.f, 0.f}, a3 = {0.f, 0.f};
        v2 u0 = {0.f, 0.f}, u1 = {0.f, 0.f}, u2 = {0.f, 0.f}, u3 = {0.f, 0.f};
#pragma unroll
        for (int q = 0; q < 7; ++q) {
            float4 hq0 = hv[2 * q];
            float4 hq1 = hv[2 * q + 1];
            v2 p0; p0.x = hq0.x; p0.y = hq0.y;
            v2 p1; p1.x = hq0.z; p1.y = hq0.w;
            v2 p2; p2.x = hq1.x; p2.y = hq1.y;
            v2 p3; p3.x = hq1.z; p3.y = hq1.w;
            a0 = __builtin_elementwise_fma(p0, whp[4 * q + 0], a0);
            a1 = __builtin_elementwise_fma(p1, whp[4 * q + 1], a1);
            a2 = __builtin_elementwise_fma(p2, whp[4 * q + 2], a2);
            a3 = __builtin_elementwise_fma(p3, whp[4 * q + 3], a3);
            u0 = __builtin_elementwise_fma(p0, wtcp[4 * q + 0], u0);
            u1 = __builtin_elementwise_fma(p1, wtcp[4 * q + 1], u1);
            u2 = __builtin_elementwise_fma(p2, wtcp[4 * q + 2], u2);
            u3 = __builtin_elementwise_fma(p3, wtcp[4 * q + 3], u3);
        }
        v2 s = (a0 + a1) + (a2 + a3);
        v2 us = (u0 + u1) + (u2 + u3);
        vsv = (boutl + us.x) + us.y;                  // vs for step t-1 (h_t @ wout)
        float z2 = (gcur + s.x) + s.y;                // log2 domain
        float zc = fmaxf(z2, -80.f);                  // keep e finite
        float e = __builtin_amdgcn_exp2f(-zc);
        float t1 = 1.f + e;
        float num = fmaf(h, t1, alpha);
        float den = fmaf(cden, t1, DT);
        float hn = num * rcpf(den);
        // Pin: 1 ds_write, then ALL 14 ds_reads contiguous, then the VALU pack.
        __builtin_amdgcn_sched_group_barrier(0x200, 1, 0);   // DS write
        __builtin_amdgcn_sched_group_barrier(0x100, 14, 0);  // DS reads
        __builtin_amdgcn_sched_group_barrier(0x002, 72, 0);  // VALU
        return hn;
    };

    const bool vlane = lane < LEVELS;
    float h = 0.f;
    float vsv;
    float4 gq = gv4[0];
    for (int tq = 0; tq < TSTEPS / 4; ++tq) {
        float4 gn = gq;
        if (tq + 1 < TSTEPS / 4) gn = gv4[tq + 1];   // prefetch ~4 steps ahead
        const size_t tb = (size_t)(4 * tq) * VAR_N * LEVELS;
        h = cell(h, gq.x, vsv);
        if (tq > 0 && vlane) vsb[tb - (size_t)VAR_N * LEVELS] = vsv;
        h = cell(h, gq.y, vsv);
        if (vlane) vsb[tb] = vsv;
        h = cell(h, gq.z, vsv);
        if (vlane) vsb[tb + (size_t)VAR_N * LEVELS] = vsv;
        h = cell(h, gq.w, vsv);
        if (vlane) vsb[tb + (size_t)2 * VAR_N * LEVELS] = vsv;
        gq = gn;
    }

    // ---- tail: vs[4095] from final h, then autoregressive pred phase ----
    float wxcol[LEVELS];
#pragma unroll
    for (int l = 0; l < LEVELS; ++l)
        wxcol[l] = active ? wx[(v * LEVELS + l) * NCELLS + lane] * LOG2E : 0.f;
    const float bj = active ? b[v * NCELLS + lane] * LOG2E : 0.f;

    float vv = boutl;
#pragma unroll
    for (int k = 0; k < NCELLS; ++k) {
        float wk = (k & 1) ? wtcp[k >> 1].y : wtcp[k >> 1].x;
        vv = fmaf(rl(h, k), wk, vv);
    }
    if (vlane) vsb[(size_t)(TSTEPS - 1) * VAR_N * LEVELS] = vv;

    for (int i = 0; i < PRED_N; ++i) {
        float z2 = bj;
#pragma unroll
        for (int l = 0; l < LEVELS; ++l) z2 = fmaf(rl(vv, l), wxcol[l], z2);
#pragma unroll
        for (int k = 0; k < NCELLS; ++k) {
            float wk = (k & 1) ? whp[k >> 1].y : whp[k >> 1].x;
            z2 = fmaf(rl(h, k), wk, z2);
        }
        float zc = fmaxf(z2, -80.f);
        float e = __builtin_amdgcn_exp2f(-zc);
        float t1 = 1.f + e;
        h = fmaf(h, t1, alpha) * rcpf(fmaf(cden, t1, DT));
        vv = boutl;
#pragma unroll
        for (int k = 0; k < NCELLS; ++k) {
            float wk = (k & 1) ? wtcp[k >> 1].y : wtcp[k >> 1].x;
            vv = fmaf(rl(h, k), wk, vv);
        }
        if (vlane) vsb[(size_t)(TSTEPS + i) * VAR_N * LEVELS] = vv;
    }
}

// ---------------------------------------------------------------------------
// Kernel 3: c1 (+relu) and c2 encoders FUSED. Block = 8 t-values:
// c1 over 32 (t,var)-rows (17->17->17->68->68->68), y tile stays in LDS as
// the 8x272 c2 input, then c2 (272->272->272->68->68->68) -> out.
// ---------------------------------------------------------------------------
#define TB 8

static __device__ __forceinline__ void layer32(const float* __restrict__ in, int si,
                                               float* __restrict__ outb, int so,
                                               const float* __restrict__ W,
                                               const float* __restrict__ B,
                                               int din, int dout, bool act, int tid) {
    if (tid < dout) {
        const int j = tid;
        float acc[32];
        float bj = B[j];
#pragma unroll
        for (int r = 0; r < 32; ++r) acc[r] = bj;
        int k = 0;
        for (; k + 4 <= din; k += 4) {
            float w0 = W[(k + 0) * dout + j];
            float w1 = W[(k + 1) * dout + j];
            float w2 = W[(k + 2) * dout + j];
            float w3 = W[(k + 3) * dout + j];
#pragma unroll
            for (int r = 0; r < 32; ++r) {
                const float4 hx = *(const float4*)(in + r * si + k);
                acc[r] = fmaf(hx.x, w0, fmaf(hx.y, w1,
                          fmaf(hx.z, w2, fmaf(hx.w, w3, acc[r]))));
            }
        }
        for (; k < din; ++k) {
            float wv = W[k * dout + j];
#pragma unroll
            for (int r = 0; r < 32; ++r) acc[r] = fmaf(in[r * si + k], wv, acc[r]);
        }
#pragma unroll
        for (int r = 0; r < 32; ++r)
            outb[r * so + j] = act ? fmaxf(acc[r], 0.f) : acc[r];
    }
}

static __device__ __forceinline__ void layer8(const float* __restrict__ in,
                                              float* __restrict__ outb,
                                              const float* __restrict__ W,
                                              const float* __restrict__ B,
                                              int din, int dout, bool act, int tid) {
    for (int j = tid; j < dout; j += 256) {
        float acc[TB];
        float bj = B[j];
#pragma unroll
        for (int r = 0; r < TB; ++r) acc[r] = bj;
        int k = 0;
        for (; k + 4 <= din; k += 4) {
            float w0 = W[(size_t)(k + 0) * dout + j];
            float w1 = W[(size_t)(k + 1) * dout + j];
            float w2 = W[(size_t)(k + 2) * dout + j];
            float w3 = W[(size_t)(k + 3) * dout + j];
#pragma unroll
            for (int r = 0; r < TB; ++r) {
                const float4 hx = *(const float4*)(in + r * 272 + k);
                acc[r] = fmaf(hx.x, w0, fmaf(hx.y, w1,
                          fmaf(hx.z, w2, fmaf(hx.w, w3, acc[r]))));
            }
        }
        for (; k < din; ++k) {
            float wv = W[(size_t)k * dout + j];
#pragma unroll
            for (int r = 0; r < TB; ++r) acc[r] = fmaf(in[r * 272 + k], wv, acc[r]);
        }
#pragma unroll
        for (int r = 0; r < TB; ++r)
            outb[r * 272 + j] = act ? fmaxf(acc[r], 0.f) : acc[r];
    }
}

__global__ void c1c2_kernel(const float* __restrict__ vs,
                            const float* __restrict__ c1w1, const float* __restrict__ c1b1,
                            const float* __restrict__ c1w2, const float* __restrict__ c1b2,
                            const float* __restrict__ c1w3, const float* __restrict__ c1b3,
                            const float* __restrict__ c1w4, const float* __restrict__ c1b4,
                            const float* __restrict__ c1w5, const float* __restrict__ c1b5,
                            const float* __restrict__ c2w1, const float* __restrict__ c2b1,
                            const float* __restrict__ c2w2, const float* __restrict__ c2b2,
                            const float* __restrict__ c2w3, const float* __restrict__ c2b3,
                            const float* __restrict__ c2w4, const float* __restrict__ c2b4,
                            const float* __restrict__ c2w5, const float* __restrict__ c2b5,
                            float* __restrict__ out) {
    __shared__ __align__(16) float bA[32 * 20];
    __shared__ __align__(16) float bB[32 * 20];
    __shared__ __align__(16) float bY[TB * 272];   // also viewed as 32 x 68
    __shared__ __align__(16) float bZ[TB * 272];
    const int t0 = blockIdx.x * TB;
    const int tid = threadIdx.x;

    // stage vs rows: row = tq*4+v, 17 cols, stride 20
    for (int idx = tid; idx < TB * 4 * LEVELS; idx += 256) {
        int row = idx / LEVELS, l = idx - row * LEVELS;
        int t = t0 + (row >> 2);
        bA[row * 20 + l] = (t < TROWS) ? vs[((size_t)t * VAR_N + (row & 3)) * LEVELS + l] : 0.f;
    }
    __syncthreads();

    layer32(bA, 20, bB, 20, c1w1, c1b1, 17, 17, true, tid);  __syncthreads();
    layer32(bB, 20, bA, 20, c1w2, c1b2, 17, 17, true, tid);  __syncthreads();
    layer32(bA, 20, bY, 68, c1w3, c1b3, 17, 68, true, tid);  __syncthreads();
    layer32(bY, 68, bZ, 68, c1w4, c1b4, 68, 68, true, tid);  __syncthreads();
    layer32(bZ, 68, bY, 68, c1w5, c1b5, 68, 68, true, tid);  __syncthreads();
    // bY is now the 8 x 272 c2 input ((tq*4+v)*68 + c == tq*272 + v*68 + c)
    layer8(bY, bZ, c2w1, c2b1, 272, 272, true, tid);  __syncthreads();
    layer8(bZ, bY, c2w2, c2b2, 272, 272, true, tid);  __syncthreads();
    layer8(bY, bZ, c2w3, c2b3, 272, 68, true, tid);   __syncthreads();
    layer8(bZ, bY, c2w4, c2b4, 68, 68, true, tid);    __syncthreads();
    layer8(bY, bZ, c2w5, c2b5, 68, 68, false, tid);   __syncthreads();

    for (int idx = tid; idx < TB * 68; idx += 256) {
        int tq = idx / 68, c = idx - tq * 68;
        int t = t0 + tq;
        if (t < TROWS) out[(size_t)t * 68 + c] = bZ[tq * 272 + c];
    }
}

// ---------------------------------------------------------------------------
extern "C" void kernel_launch(void* const* d_in, const int* in_sizes, int n_in,
                              void* d_out, int out_size, void* d_ws, size_t ws_size,
                              hipStream_t stream) {
    const float* x = (const float*)d_in[0];
    const float* pw[5] = {(const float*)d_in[1], (const float*)d_in[3], (const float*)d_in[5],
                          (const float*)d_in[7], (const float*)d_in[9]};
    const float* pb[5] = {(const float*)d_in[2], (const float*)d_in[4], (const float*)d_in[6],
                          (const float*)d_in[8], (const float*)d_in[10]};
    const float* c1w[5] = {(const float*)d_in[11], (const float*)d_in[13], (const float*)d_in[15],
                           (const float*)d_in[17], (const float*)d_in[19]};
    const float* c1b[5] = {(const float*)d_in[12], (const float*)d_in[14], (const float*)d_in[16],
                           (const float*)d_in[18], (const float*)d_in[20]};
    const float* c2w[5] = {(const float*)d_in[21], (const float*)d_in[23], (const float*)d_in[25],
                           (const float*)d_in[27], (const float*)d_in[29]};
    const float* c2b[5] = {(const float*)d_in[22], (const float*)d_in[24], (const float*)d_in[26],
                           (const float*)d_in[28], (const float*)d_in[30]};
    const float* ltc_wx = (const float*)d_in[31];
    const float* ltc_wh = (const float*)d_in[32];
    const float* ltc_b = (const float*)d_in[33];
    const float* ltc_a = (const float*)d_in[34];
    const float* ltc_tau = (const float*)d_in[35];
    const float* ltc_wout = (const float*)d_in[36];
    const float* ltc_bout = (const float*)d_in[37];

    float* ws = (float*)d_ws;
    float* g = ws;                         // 4*56*4096 = 917504 (transposed, LOG2E-scaled)
    float* vs_t = g + 917504;              // 4108*4*17 = 279344
    float* out = (float*)d_out;            // 4108*68

    // 1) preproc encoder + gprep fused: x(4096,68) -> g[v][j][t]
    pre_g_kernel<<<TSTEPS / RPB, 256, 0, stream>>>(
        x, pw[0], pb[0], pw[1], pb[1], pw[2], pb[2], pw[3], pb[3], pw[4], pb[4],
        ltc_wx, ltc_b, g);

    // 2) sequential LTC scan (1 wave per var), projection fused -> vs_t
    scan_kernel<<<VAR_N, 64, 0, stream>>>(g, ltc_wh, ltc_a, ltc_tau, ltc_wx,
                                          ltc_wout, ltc_bout, ltc_b, vs_t);

    // 3) c1 (+relu) and c2 encoders fused: vs_t -> out
    c1c2_kernel<<<(TROWS + TB - 1) / TB, 256, 0, stream>>>(
        vs_t,
        c1w[0], c1b[0], c1w[1], c1b[1], c1w[2], c1b[2], c1w[3], c1b[3], c1w[4], c1b[4],
        c2w[0], c2b[0], c2w[1], c2b[1], c2w[2], c2b[2], c2w[3], c2b[3], c2w[4], c2b[4],
        out);
}

// Round 8
// 1107.359 us; speedup vs baseline: 1.2049x; 1.2049x over previous
//
#include <hip/hip_runtime.h>
#include <hip/hip_bf16.h>
#include <math.h>

#define VAR_N 4
#define LEVELS 17
#define NCELLS 56
#define PRED_N 12
#define TSTEPS 4096
#define TROWS (TSTEPS + PRED_N)
#define DT 0.1f
#define RPB 8
#define LOG2E 1.44269504088896340736f
#define TB 16

static __device__ __forceinline__ float rl(float x, int lane) {
    return __int_as_float(__builtin_amdgcn_readlane(__float_as_int(x), lane));
}
static __device__ __forceinline__ float rcpf(float x) {
    return __builtin_amdgcn_rcpf(x);
}

// ---------------------------------------------------------------------------
// Kernel 1: preproc encoder (68->68 x5) fused with gprep (unchanged from R7).
// ---------------------------------------------------------------------------
__global__ void pre_g_kernel(const float* __restrict__ x,
                             const float* __restrict__ w1, const float* __restrict__ b1,
                             const float* __restrict__ w2, const float* __restrict__ b2,
                             const float* __restrict__ w3, const float* __restrict__ b3,
                             const float* __restrict__ w4, const float* __restrict__ b4,
                             const float* __restrict__ w5, const float* __restrict__ b5,
                             const float* __restrict__ wx, const float* __restrict__ bvec,
                             float* __restrict__ g) {
    __shared__ float lds[2 * RPB * 68];
    float* bufA = lds;
    float* bufB = lds + RPB * 68;
    const int r0 = blockIdx.x * RPB;
    const int tid = threadIdx.x;

    for (int idx = tid; idx < RPB * 68; idx += 256)
        bufA[idx] = x[(size_t)r0 * 68 + idx];
    __syncthreads();

    const float* Ws[5] = {w1, w2, w3, w4, w5};
    const float* Bs[5] = {b1, b2, b3, b4, b5};
    for (int L = 0; L < 5; ++L) {
        const float* __restrict__ W = Ws[L];
        const bool act = (L < 4);
        if (tid < 68) {
            const int j = tid;
            float acc[RPB];
            float bj = Bs[L][j];
#pragma unroll
            for (int r = 0; r < RPB; ++r) acc[r] = bj;
            for (int k = 0; k + 4 <= 68; k += 4) {
                float w0v = W[(k + 0) * 68 + j];
                float w1v = W[(k + 1) * 68 + j];
                float w2v = W[(k + 2) * 68 + j];
                float w3v = W[(k + 3) * 68 + j];
#pragma unroll
                for (int r = 0; r < RPB; ++r) {
                    const float4 hx = *(const float4*)(bufA + r * 68 + k);
                    acc[r] = fmaf(hx.x, w0v, fmaf(hx.y, w1v,
                              fmaf(hx.z, w2v, fmaf(hx.w, w3v, acc[r]))));
                }
            }
#pragma unroll
            for (int r = 0; r < RPB; ++r)
                bufB[r * 68 + j] = act ? fmaxf(acc[r], 0.f) : acc[r];
        }
        __syncthreads();
        float* t = bufA; bufA = bufB; bufB = t;
    }

    for (int idx = tid; idx < RPB * 4 * NCELLS; idx += 256) {
        int r = idx / 224;
        int rem = idx - r * 224;
        int q = rem / NCELLS;
        int j = rem - q * NCELLS;
        int gr = r0 + r;
        int v = gr >> 10;
        int trow = ((gr & 1023) << 2) + q;
        const float* arow = bufA + r * 68 + q * LEVELS;
        float acc = bvec[v * NCELLS + j];
#pragma unroll
        for (int l = 0; l < LEVELS; ++l)
            acc = fmaf(arow[l], wx[(v * LEVELS + l) * NCELLS + j], acc);
        g[((size_t)(v * NCELLS + j)) * TSTEPS + trow] = acc * LOG2E;
    }
}

// ---------------------------------------------------------------------------
// Kernel 2: sequential LTC scan (R6 internals — proven 772 us). Writes raw
// h into H[v][t][j] for ALL 4108 steps (observed + pred). No projection in
// the hot loop (R7 showed any addition to `cell` costs ~1:1 issue time).
// ---------------------------------------------------------------------------
__global__ void __launch_bounds__(64, 1) scan_kernel(
    const float* __restrict__ g, const float* __restrict__ wh,
    const float* __restrict__ a, const float* __restrict__ tau,
    const float* __restrict__ wx, const float* __restrict__ wout,
    const float* __restrict__ bout, const float* __restrict__ b,
    float* __restrict__ H) {
    typedef float v2 __attribute__((ext_vector_type(2)));
    const int v = blockIdx.x;
    const int lane = threadIdx.x;
    const bool active = lane < NCELLS;
    const int j = active ? lane : (NCELLS - 1);
    __shared__ __align__(16) float hbuf[64];

    v2 whp[28];
#pragma unroll
    for (int q = 0; q < 28; ++q) {
        float w0 = active ? wh[((size_t)v * NCELLS + 2 * q + 0) * NCELLS + lane] * LOG2E : 0.f;
        float w1 = active ? wh[((size_t)v * NCELLS + 2 * q + 1) * NCELLS + lane] * LOG2E : 0.f;
        v2 t; t.x = w0; t.y = w1;
        whp[q] = t;
    }
    const float alpha = active ? DT * a[v * NCELLS + lane] : 0.f;
    const float cden = active ? 1.f + DT / (tau[v * NCELLS + lane] + 0.5f) : 1.f;

    const float4* __restrict__ gv4 = (const float4*)(g + ((size_t)v * NCELLS + j) * TSTEPS);
    float* __restrict__ hp = H + (size_t)v * TROWS * NCELLS + lane;

    auto cell = [&](float h, float gcur) -> float {
        hbuf[lane] = h;   // ds_write; same-wave DS pipe ordering, no barrier
        const float4* h4 = (const float4*)hbuf;
        float4 hv[14];
#pragma unroll
        for (int q = 0; q < 14; ++q) hv[q] = h4[q];   // 14 ds_read_b128, broadcast
        v2 a0 = {0.f, 0.f}, a1 = {0.f, 0.f}, a2 = {0.f, 0.f}, a3 = {0.f, 0.f};
#pragma unroll
        for (int q = 0; q < 7; ++q) {
            float4 hq0 = hv[2 * q];
            float4 hq1 = hv[2 * q + 1];
            v2 p0; p0.x = hq0.x; p0.y = hq0.y;
            v2 p1; p1.x = hq0.z; p1.y = hq0.w;
            v2 p2; p2.x = hq1.x; p2.y = hq1.y;
            v2 p3; p3.x = hq1.z; p3.y = hq1.w;
            a0 = __builtin_elementwise_fma(p0, whp[4 * q + 0], a0);
            a1 = __builtin_elementwise_fma(p1, whp[4 * q + 1], a1);
            a2 = __builtin_elementwise_fma(p2, whp[4 * q + 2], a2);
            a3 = __builtin_elementwise_fma(p3, whp[4 * q + 3], a3);
        }
        v2 s = (a0 + a1) + (a2 + a3);
        float z2 = (gcur + s.x) + s.y;                // log2 domain
        float zc = fmaxf(z2, -80.f);                  // keep e finite
        float e = __builtin_amdgcn_exp2f(-zc);
        float t1 = 1.f + e;
        float num = fmaf(h, t1, alpha);
        float den = fmaf(cden, t1, DT);
        float hn = num * rcpf(den);
        __builtin_amdgcn_sched_group_barrier(0x200, 1, 0);   // DS write
        __builtin_amdgcn_sched_group_barrier(0x100, 14, 0);  // DS reads
        __builtin_amdgcn_sched_group_barrier(0x002, 40, 0);  // VALU
        return hn;
    };

    float h = 0.f;
    float4 gq = gv4[0];
    for (int tq = 0; tq < TSTEPS / 4; ++tq) {
        float4 gn = gq;
        if (tq + 1 < TSTEPS / 4) gn = gv4[tq + 1];   // prefetch ~4 steps ahead
        h = cell(h, gq.x); if (active) hp[0 * NCELLS] = h;
        h = cell(h, gq.y); if (active) hp[1 * NCELLS] = h;
        h = cell(h, gq.z); if (active) hp[2 * NCELLS] = h;
        h = cell(h, gq.w); if (active) hp[3 * NCELLS] = h;
        hp += 4 * NCELLS;
        gq = gn;
    }

    // ---- autoregressive pred phase (12 steps; readlane is fine here) ----
    float wxcol[LEVELS];
#pragma unroll
    for (int l = 0; l < LEVELS; ++l)
        wxcol[l] = active ? wx[(v * LEVELS + l) * NCELLS + lane] * LOG2E : 0.f;
    float wtc[NCELLS];  // lane l (<17) holds wout[:, l]
#pragma unroll
    for (int jj = 0; jj < NCELLS; ++jj)
        wtc[jj] = (lane < LEVELS) ? wout[((size_t)v * NCELLS + jj) * LEVELS + lane] : 0.f;
    const float bj = active ? b[v * NCELLS + lane] * LOG2E : 0.f;
    const float boutl = (lane < LEVELS) ? bout[v * LEVELS + lane] : 0.f;

    float vv = boutl;
#pragma unroll
    for (int jj = 0; jj < NCELLS; ++jj) vv = fmaf(rl(h, jj), wtc[jj], vv);

    for (int i = 0; i < PRED_N; ++i) {
        float z2 = bj;
#pragma unroll
        for (int l = 0; l < LEVELS; ++l) z2 = fmaf(rl(vv, l), wxcol[l], z2);
#pragma unroll
        for (int k = 0; k < NCELLS; ++k) {
            float wk = (k & 1) ? whp[k >> 1].y : whp[k >> 1].x;
            z2 = fmaf(rl(h, k), wk, z2);
        }
        float zc = fmaxf(z2, -80.f);
        float e = __builtin_amdgcn_exp2f(-zc);
        float t1 = 1.f + e;
        h = fmaf(h, t1, alpha) * rcpf(fmaf(cden, t1, DT));
        if (active) hp[0] = h;     // H row TSTEPS+i
        hp += NCELLS;
        vv = boutl;
#pragma unroll
        for (int jj = 0; jj < NCELLS; ++jj) vv = fmaf(rl(h, jj), wtc[jj], vv);
    }
}

// ---------------------------------------------------------------------------
// Kernel 3: c1+c2 fused, reading raw H. c1's first layer uses COMPOSED
// weights W1eff[v] = wout[v] @ c1w1 (the proj is linear -> folded, so the
// proj kernel/pass disappears). TB=16 t-rows per block; block=320 threads so
// the 272-wide c2 layers run in one pass.
// ---------------------------------------------------------------------------
__global__ void __launch_bounds__(320) c1c2_kernel(
    const float* __restrict__ H,
    const float* __restrict__ wout, const float* __restrict__ bout,
    const float* __restrict__ c1w1, const float* __restrict__ c1b1,
    const float* __restrict__ c1w2, const float* __restrict__ c1b2,
    const float* __restrict__ c1w3, const float* __restrict__ c1b3,
    const float* __restrict__ c1w4, const float* __restrict__ c1b4,
    const float* __restrict__ c1w5, const float* __restrict__ c1b5,
    const float* __restrict__ c2w1, const float* __restrict__ c2b1,
    const float* __restrict__ c2w2, const float* __restrict__ c2b2,
    const float* __restrict__ c2w3, const float* __restrict__ c2b3,
    const float* __restrict__ c2w4, const float* __restrict__ c2b4,
    const float* __restrict__ c2w5, const float* __restrict__ c2b5,
    float* __restrict__ out) {
    __shared__ __align__(16) float sH[64 * 56];        // rows (rt*4+v) x 56
    __shared__ __align__(16) float sW1[4 * 17 * 56];   // W1eff [v][l][k]
    __shared__ float sB1[4 * 17];
    __shared__ __align__(16) float bA[64 * 20];
    __shared__ __align__(16) float bB[64 * 20];
    __shared__ __align__(16) float bY[TB * 272];
    __shared__ __align__(16) float bZ[TB * 272];
    const int t0 = blockIdx.x * TB;
    const int tid = threadIdx.x;

    // ---- compose W1eff[v][l][k] = sum_m wout[v][k][m] * c1w1[m][l] ----
    for (int idx = tid; idx < 4 * 17 * 56; idx += 320) {
        int v = idx / (17 * 56);
        int rem = idx - v * (17 * 56);
        int l = rem / 56, k = rem - (rem / 56) * 56;
        float acc = 0.f;
#pragma unroll
        for (int m = 0; m < 17; ++m)
            acc = fmaf(wout[(v * 56 + k) * 17 + m], c1w1[m * 17 + l], acc);
        sW1[idx] = acc;
    }
    for (int idx = tid; idx < 68; idx += 320) {
        int v = idx / 17, l = idx - (idx / 17) * 17;
        float acc = c1b1[l];
#pragma unroll
        for (int m = 0; m < 17; ++m)
            acc = fmaf(bout[v * 17 + m], c1w1[m * 17 + l], acc);
        sB1[idx] = acc;
    }
    // ---- stage H rows ----
    for (int idx = tid; idx < 64 * 56; idx += 320) {
        int row = idx / 56, j = idx - (idx / 56) * 56;
        int rt = row >> 2, v = row & 3;
        int t = t0 + rt;
        sH[idx] = (t < TROWS) ? H[((size_t)v * TROWS + t) * 56 + j] : 0.f;
    }
    __syncthreads();

    // ---- c1 L1 (composed: 56 -> 17, relu) ----
    if (tid < 272) {
        int l = tid % 17, s = tid / 17;    // s: v = s&3, q = s>>2
        int v = s & 3, q = s >> 2;
        const float* Wrow = sW1 + (v * 17 + l) * 56;
        float bl = sB1[v * 17 + l];
        float acc[4];
#pragma unroll
        for (int r = 0; r < 4; ++r) acc[r] = bl;
        for (int k = 0; k < 56; k += 4) {
            float4 w = *(const float4*)(Wrow + k);
#pragma unroll
            for (int r = 0; r < 4; ++r) {
                const float4 hx = *(const float4*)(sH + ((4 * q + r) * 4 + v) * 56 + k);
                acc[r] = fmaf(hx.x, w.x, fmaf(hx.y, w.y,
                          fmaf(hx.z, w.z, fmaf(hx.w, w.w, acc[r]))));
            }
        }
#pragma unroll
        for (int r = 0; r < 4; ++r)
            bA[((4 * q + r) * 4 + v) * 20 + l] = fmaxf(acc[r], 0.f);
    }
    __syncthreads();

    // ---- c1 L2 (17 -> 17, relu) ----
    if (tid < 272) {
        int l = tid % 17, s = tid / 17;    // rows 4s..4s+3
        float acc[4];
        float bl = c1b2[l];
#pragma unroll
        for (int r = 0; r < 4; ++r) acc[r] = bl;
        for (int k = 0; k + 4 <= 17; k += 4) {
            float w0 = c1w2[(k + 0) * 17 + l], w1 = c1w2[(k + 1) * 17 + l];
            float w2 = c1w2[(k + 2) * 17 + l], w3 = c1w2[(k + 3) * 17 + l];
#pragma unroll
            for (int r = 0; r < 4; ++r) {
                const float4 hx = *(const float4*)(bA + (4 * s + r) * 20 + k);
                acc[r] = fmaf(hx.x, w0, fmaf(hx.y, w1, fmaf(hx.z, w2, fmaf(hx.w, w3, acc[r]))));
            }
        }
        float w16 = c1w2[16 * 17 + l];
#pragma unroll
        for (int r = 0; r < 4; ++r) {
            acc[r] = fmaf(bA[(4 * s + r) * 20 + 16], w16, acc[r]);
            bB[(4 * s + r) * 20 + l] = fmaxf(acc[r], 0.f);
        }
    }
    __syncthreads();

    // ---- c1 L3 (17 -> 68, relu) -> bY rows*68 ----
    if (tid < 272) {
        int j = tid % 68, gr = tid / 68;   // rows 16gr..16gr+15
        float acc[16];
        float bj = c1b3[j];
#pragma unroll
        for (int r = 0; r < 16; ++r) acc[r] = bj;
        for (int k = 0; k + 4 <= 17; k += 4) {
            float w0 = c1w3[(k + 0) * 68 + j], w1 = c1w3[(k + 1) * 68 + j];
            float w2 = c1w3[(k + 2) * 68 + j], w3 = c1w3[(k + 3) * 68 + j];
#pragma unroll
            for (int r = 0; r < 16; ++r) {
                const float4 hx = *(const float4*)(bB + (16 * gr + r) * 20 + k);
                acc[r] = fmaf(hx.x, w0, fmaf(hx.y, w1, fmaf(hx.z, w2, fmaf(hx.w, w3, acc[r]))));
            }
        }
        float w16 = c1w3[16 * 68 + j];
#pragma unroll
        for (int r = 0; r < 16; ++r) {
            acc[r] = fmaf(bB[(16 * gr + r) * 20 + 16], w16, acc[r]);
            bY[(16 * gr + r) * 68 + j] = fmaxf(acc[r], 0.f);
        }
    }
    __syncthreads();

    // ---- c1 L4 / L5 (68 -> 68, both relu: L5 carries the outer relu) ----
#pragma unroll
    for (int LL = 0; LL < 2; ++LL) {
        const float* W = LL ? c1w5 : c1w4;
        const float* B = LL ? c1b5 : c1b4;
        const float* inb = LL ? bZ : bY;
        float* outb = LL ? bY : bZ;
        if (tid < 272) {
            int j = tid % 68, gr = tid / 68;
            float acc[16];
            float bj = B[j];
#pragma unroll
            for (int r = 0; r < 16; ++r) acc[r] = bj;
            for (int k = 0; k < 68; k += 4) {
                float w0 = W[(k + 0) * 68 + j], w1 = W[(k + 1) * 68 + j];
                float w2 = W[(k + 2) * 68 + j], w3 = W[(k + 3) * 68 + j];
#pragma unroll
                for (int r = 0; r < 16; ++r) {
                    const float4 hx = *(const float4*)(inb + (16 * gr + r) * 68 + k);
                    acc[r] = fmaf(hx.x, w0, fmaf(hx.y, w1, fmaf(hx.z, w2, fmaf(hx.w, w3, acc[r]))));
                }
            }
#pragma unroll
            for (int r = 0; r < 16; ++r)
                outb[(16 * gr + r) * 68 + j] = fmaxf(acc[r], 0.f);
        }
        __syncthreads();
    }
    // bY now = 16 x 272 c2 input ((rt*4+v)*68+c == rt*272 + v*68+c)

    // ---- c2 L1 / L2 (272 -> 272, relu) ----
#pragma unroll
    for (int LL = 0; LL < 2; ++LL) {
        const float* W = LL ? c2w2 : c2w1;
        const float* B = LL ? c2b2 : c2b1;
        const float* inb = LL ? bZ : bY;
        float* outb = LL ? bY : bZ;
        if (tid < 272) {
            int j = tid;
            float acc[16];
            float bj = B[j];
#pragma unroll
            for (int r = 0; r < 16; ++r) acc[r] = bj;
            for (int k = 0; k < 272; k += 4) {
                float w0 = W[(size_t)(k + 0) * 272 + j], w1 = W[(size_t)(k + 1) * 272 + j];
                float w2 = W[(size_t)(k + 2) * 272 + j], w3 = W[(size_t)(k + 3) * 272 + j];
#pragma unroll
                for (int r = 0; r < 16; ++r) {
                    const float4 hx = *(const float4*)(inb + r * 272 + k);
                    acc[r] = fmaf(hx.x, w0, fmaf(hx.y, w1, fmaf(hx.z, w2, fmaf(hx.w, w3, acc[r]))));
                }
            }
#pragma unroll
            for (int r = 0; r < 16; ++r)
                outb[r * 272 + j] = fmaxf(acc[r], 0.f);
        }
        __syncthreads();
    }

    // ---- c2 L3 (272 -> 68, relu) -> bZ as 16 x 68 ----
    if (tid < 272) {
        int j = tid % 68, gr = tid / 68;   // rows 4gr..4gr+3
        float acc[4];
        float bj = c2b3[j];
#pragma unroll
        for (int r = 0; r < 4; ++r) acc[r] = bj;
        for (int k = 0; k < 272; k += 4) {
            float w0 = c2w3[(size_t)(k + 0) * 68 + j], w1 = c2w3[(size_t)(k + 1) * 68 + j];
            float w2 = c2w3[(size_t)(k + 2) * 68 + j], w3 = c2w3[(size_t)(k + 3) * 68 + j];
#pragma unroll
            for (int r = 0; r < 4; ++r) {
                const float4 hx = *(const float4*)(bY + (4 * gr + r) * 272 + k);
                acc[r] = fmaf(hx.x, w0, fmaf(hx.y, w1, fmaf(hx.z, w2, fmaf(hx.w, w3, acc[r]))));
            }
        }
#pragma unroll
        for (int r = 0; r < 4; ++r)
            bZ[(4 * gr + r) * 68 + j] = fmaxf(acc[r], 0.f);
    }
    __syncthreads();

    // ---- c2 L4 (68 -> 68, relu) bZ -> bA-view? use bY as 16x68 ----
    if (tid < 272) {
        int j = tid % 68, gr = tid / 68;
        float acc[4];
        float bj = c2b4[j];
#pragma unroll
        for (int r = 0; r < 4; ++r) acc[r] = bj;
        for (int k = 0; k < 68; k += 4) {
            float w0 = c2w4[(k + 0) * 68 + j], w1 = c2w4[(k + 1) * 68 + j];
            float w2 = c2w4[(k + 2) * 68 + j], w3 = c2w4[(k + 3) * 68 + j];
#pragma unroll
            for (int r = 0; r < 4; ++r) {
                const float4 hx = *(const float4*)(bZ + (4 * gr + r) * 68 + k);
                acc[r] = fmaf(hx.x, w0, fmaf(hx.y, w1, fmaf(hx.z, w2, fmaf(hx.w, w3, acc[r]))));
            }
        }
#pragma unroll
        for (int r = 0; r < 4; ++r)
            bY[(4 * gr + r) * 68 + j] = fmaxf(acc[r], 0.f);
    }
    __syncthreads();

    // ---- c2 L5 (68 -> 68, no relu) bY -> bZ ----
    if (tid < 272) {
        int j = tid % 68, gr = tid / 68;
        float acc[4];
        float bj = c2b5[j];
#pragma unroll
        for (int r = 0; r < 4; ++r) acc[r] = bj;
        for (int k = 0; k < 68; k += 4) {
            float w0 = c2w5[(k + 0) * 68 + j], w1 = c2w5[(k + 1) * 68 + j];
            float w2 = c2w5[(k + 2) * 68 + j], w3 = c2w5[(k + 3) * 68 + j];
#pragma unroll
            for (int r = 0; r < 4; ++r) {
                const float4 hx = *(const float4*)(bY + (4 * gr + r) * 68 + k);
                acc[r] = fmaf(hx.x, w0, fmaf(hx.y, w1, fmaf(hx.z, w2, fmaf(hx.w, w3, acc[r]))));
            }
        }
#pragma unroll
        for (int r = 0; r < 4; ++r)
            bZ[(4 * gr + r) * 68 + j] = acc[r];
    }
    __syncthreads();

    for (int idx = tid; idx < TB * 68; idx += 320) {
        int r = idx / 68, c = idx - (idx / 68) * 68;
        int t = t0 + r;
        if (t < TROWS) out[(size_t)t * 68 + c] = bZ[r * 68 + c];
    }
}

// ---------------------------------------------------------------------------
extern "C" void kernel_launch(void* const* d_in, const int* in_sizes, int n_in,
                              void* d_out, int out_size, void* d_ws, size_t ws_size,
                              hipStream_t stream) {
    const float* x = (const float*)d_in[0];
    const float* pw[5] = {(const float*)d_in[1], (const float*)d_in[3], (const float*)d_in[5],
                          (const float*)d_in[7], (const float*)d_in[9]};
    const float* pb[5] = {(const float*)d_in[2], (const float*)d_in[4], (const float*)d_in[6],
                          (const float*)d_in[8], (const float*)d_in[10]};
    const float* c1w[5] = {(const float*)d_in[11], (const float*)d_in[13], (const float*)d_in[15],
                           (const float*)d_in[17], (const float*)d_in[19]};
    const float* c1b[5] = {(const float*)d_in[12], (const float*)d_in[14], (const float*)d_in[16],
                           (const float*)d_in[18], (const float*)d_in[20]};
    const float* c2w[5] = {(const float*)d_in[21], (const float*)d_in[23], (const float*)d_in[25],
                           (const float*)d_in[27], (const float*)d_in[29]};
    const float* c2b[5] = {(const float*)d_in[22], (const float*)d_in[24], (const float*)d_in[26],
                           (const float*)d_in[28], (const float*)d_in[30]};
    const float* ltc_wx = (const float*)d_in[31];
    const float* ltc_wh = (const float*)d_in[32];
    const float* ltc_b = (const float*)d_in[33];
    const float* ltc_a = (const float*)d_in[34];
    const float* ltc_tau = (const float*)d_in[35];
    const float* ltc_wout = (const float*)d_in[36];
    const float* ltc_bout = (const float*)d_in[37];

    float* ws = (float*)d_ws;
    float* g = ws;                         // 4*56*4096 = 917504 (transposed, LOG2E-scaled)
    float* H = g + 917504;                 // 4*4108*56 = 920192 (raw h, incl. pred rows)
    float* out = (float*)d_out;            // 4108*68

    // 1) preproc encoder + gprep fused
    pre_g_kernel<<<TSTEPS / RPB, 256, 0, stream>>>(
        x, pw[0], pb[0], pw[1], pb[1], pw[2], pb[2], pw[3], pb[3], pw[4], pb[4],
        ltc_wx, ltc_b, g);

    // 2) sequential LTC scan -> raw H
    scan_kernel<<<VAR_N, 64, 0, stream>>>(g, ltc_wh, ltc_a, ltc_tau, ltc_wx,
                                          ltc_wout, ltc_bout, ltc_b, H);

    // 3) c1+c2 fused (c1 L1 composed with the LTC output projection)
    c1c2_kernel<<<(TROWS + TB - 1) / TB, 320, 0, stream>>>(
        H, ltc_wout, ltc_bout,
        c1w[0], c1b[0], c1w[1], c1b[1], c1w[2], c1b[2], c1w[3], c1b[3], c1w[4], c1b[4],
        c2w[0], c2b[0], c2w[1], c2b[1], c2w[2], c2b[2], c2w[3], c2b[3], c2w[4], c2b[4],
        out);
}